// Round 19
// baseline (109.687 us; speedup 1.0000x reference)
//
#include <hip/hip_runtime.h>
#include <hip/hip_bf16.h>
#include <math.h>

typedef __attribute__((ext_vector_type(8))) __bf16 bf16x8;
typedef __attribute__((ext_vector_type(4))) short short4v;
typedef __attribute__((ext_vector_type(4))) float f32x4;
typedef __attribute__((ext_vector_type(4))) unsigned short ushort4v;
typedef __attribute__((ext_vector_type(8))) unsigned short ushort8;

#define LOG2E 1.44269504088896340736f

extern "C" __device__ float __ocml_native_exp2_f32(float);
#if __has_builtin(__builtin_amdgcn_exp2f)
#define EXP2(x) __builtin_amdgcn_exp2f(x)
#else
#define EXP2(x) __ocml_native_exp2_f32(x)
#endif

static __device__ __forceinline__ unsigned short f2bf(float f) {
  unsigned int u = __float_as_uint(f);
  return (unsigned short)((u + 0x7fffu + ((u >> 16) & 1u)) >> 16);
}
static __device__ __forceinline__ short bfbits(float f) {
  __bf16 h = (__bf16)f;
  return __builtin_bit_cast(short, h);
}

static __device__ __forceinline__ void gload16(const unsigned short* g, void* l) {
  __builtin_amdgcn_global_load_lds(
      (const __attribute__((address_space(1))) unsigned int*)g,
      (__attribute__((address_space(3))) unsigned int*)l, 16, 0, 0);
}

// ---------------- fused prep: all casts + RoPE table ----------------
__global__ __launch_bounds__(256) void prep_kernel(
    const float* __restrict__ x, const float* __restrict__ Wq,
    const float* __restrict__ Wk, const float* __restrict__ Wv,
    const float* __restrict__ Wo,
    unsigned short* __restrict__ xb, unsigned short* __restrict__ wqkv,
    unsigned short* __restrict__ wo_b, float* __restrict__ tab) {
  const int bx = blockIdx.x, tid = threadIdx.x;
  if (bx < 6656) {
    const float* src;
    unsigned short* dst;
    int i;
    if (bx < 4096)       { src = x;  dst = xb;             i = bx * 256 + tid; }
    else if (bx < 5120)  { src = Wq; dst = wqkv;           i = (bx - 4096) * 256 + tid; }
    else if (bx < 5376)  { src = Wk; dst = wqkv + 1048576; i = (bx - 5120) * 256 + tid; }
    else if (bx < 5632)  { src = Wv; dst = wqkv + 1310720; i = (bx - 5376) * 256 + tid; }
    else                 { src = Wo; dst = wo_b;           i = (bx - 5632) * 256 + tid; }
    float4 v = reinterpret_cast<const float4*>(src)[i];
    ushort4v o;
    o.x = f2bf(v.x); o.y = f2bf(v.y); o.z = f2bf(v.z); o.w = f2bf(v.w);
    reinterpret_cast<ushort4v*>(dst)[i] = o;
  } else {
    int i = (bx - 6656) * 256 + tid;  // 65536 = 2048*32
    int s = i >> 5, d = i & 31;
    float invf = powf(10000.f, -(float)d / 32.f);
    float fr = (float)s * invf;
    tab[s * 64 + d] = cosf(fr);
    tab[s * 64 + 32 + d] = sinf(fr);
  }
}

// ---------------- fused QKV GEMM: qkv = x @ Wqkv^T + RMSNorm/RoPE/pack epilogue ----
// BM=64, BN=128, BK=64; 4 waves (2x2), wave tile 32x64 = acc[2][4].
// Q/K (bn<10): RMSNorm (xor 1/2/4/8 over lr) + RoPE (in-lane pairs n,n+2) + gain -> bf16.
// V (bn 10,11): bf16 + in-LDS transpose (reusing the staging LDS) -> vtb[d][s] directly.
__global__ __launch_bounds__(256) void gemm_qkv_kernel(
    const unsigned short* __restrict__ A, const unsigned short* __restrict__ B,
    const float* __restrict__ tab, const float* __restrict__ qg,
    unsigned short* __restrict__ qb, unsigned short* __restrict__ kb,
    unsigned short* __restrict__ vtb) {
  __shared__ unsigned short sAll[64 * 64 + 128 * 64];
  unsigned short* sA = sAll;
  unsigned short* sB = sAll + 64 * 64;
  const int t = threadIdx.x;
  const int lane = t & 63;
  const int w = t >> 6;
  const int bm = blockIdx.x / 12, bn = blockIdx.x % 12;
  const long m0 = (long)bm * 64, n0 = (long)bn * 128;
  const int wm = (w >> 1) * 32, wn = (w & 1) * 64;
  const int lr = lane & 15, lg = lane >> 4;
  f32x4 acc[2][4];
#pragma unroll
  for (int i = 0; i < 2; i++)
#pragma unroll
    for (int j = 0; j < 4; j++) acc[i][j] = (f32x4){0.f, 0.f, 0.f, 0.f};

  for (int k0 = 0; k0 < 1024; k0 += 64) {
#pragma unroll
    for (int i = 0; i < 2; i++) {
      int chunk = i * 256 + t;
      int r = chunk >> 3;
      int c = (chunk & 7) << 3;
      gload16(A + (m0 + r) * 1024 + k0 + c, (char*)sA + chunk * 16);
    }
#pragma unroll
    for (int i = 0; i < 4; i++) {
      int chunk = i * 256 + t;
      int r = chunk >> 3;
      int c = (chunk & 7) << 3;
      gload16(B + (n0 + r) * 1024 + k0 + c, (char*)sB + chunk * 16);
    }
    __syncthreads();
#pragma unroll
    for (int kk = 0; kk < 2; ++kk) {
      bf16x8 af[2], bfr[4];
#pragma unroll
      for (int m = 0; m < 2; m++)
        af[m] = *(const bf16x8*)&sA[(wm + m * 16 + lr) * 64 + kk * 32 + lg * 8];
#pragma unroll
      for (int n = 0; n < 4; n++)
        bfr[n] = *(const bf16x8*)&sB[(wn + n * 16 + lr) * 64 + kk * 32 + lg * 8];
#pragma unroll
      for (int m = 0; m < 2; m++)
#pragma unroll
        for (int n = 0; n < 4; n++)
          acc[m][n] = __builtin_amdgcn_mfma_f32_16x16x32_bf16(af[m], bfr[n], acc[m][n], 0, 0, 0);
    }
    __syncthreads();
  }
  // ---- fused epilogue ----
  const int bb = (int)(m0 >> 11);          // batch (64-row tile never straddles b)
  const int s_base = (int)(m0 & 2047) + wm + lg * 4;
  const int hsel = wn >> 6;                // which head of the 128-col block
  if (bn < 10) {
    float gscale = 1.0f;
    unsigned short* dstb;
    if (bn < 8) {
      gscale = qg[2 * bn + hsel] * (0.125f * LOG2E);
      dstb = qb + (size_t)(bb * 16 + 2 * bn + hsel) * 2048 * 64;
    } else {
      dstb = kb + (size_t)(bb * 4 + 2 * (bn - 8) + hsel) * 2048 * 64;
    }
#pragma unroll
    for (int m = 0; m < 2; m++) {
#pragma unroll
      for (int j = 0; j < 4; j++) {
        float ss = acc[m][0][j] * acc[m][0][j] + acc[m][1][j] * acc[m][1][j] +
                   acc[m][2][j] * acc[m][2][j] + acc[m][3][j] * acc[m][3][j];
        ss += __shfl_xor(ss, 1);
        ss += __shfl_xor(ss, 2);
        ss += __shfl_xor(ss, 4);
        ss += __shfl_xor(ss, 8);
        const float rinv = rsqrtf(ss * (1.0f / 64.0f) + 1.1920929e-07f);
        const int s = s_base + m * 16 + j;
        const float* tr = tab + s * 64;
        const float c0 = tr[lr], c1 = tr[16 + lr];
        const float s0 = tr[32 + lr], s1 = tr[48 + lr];
        const float n0v = acc[m][0][j] * rinv, n1v = acc[m][1][j] * rinv;
        const float n2v = acc[m][2][j] * rinv, n3v = acc[m][3][j] * rinv;
        float o0 = (n0v * c0 + n2v * s0) * gscale;
        float o1 = (n1v * c1 + n3v * s1) * gscale;
        float o2 = (n2v * c0 - n0v * s0) * gscale;
        float o3 = (n3v * c1 - n1v * s1) * gscale;
        unsigned short* d = dstb + (size_t)s * 64;
        d[lr]      = f2bf(o0);
        d[16 + lr] = f2bf(o1);
        d[32 + lr] = f2bf(o2);
        d[48 + lr] = f2bf(o3);
      }
    }
  } else {
    // V (bn 10,11): bf16 + transpose via LDS [2 heads][64 s][72 pad] -> vtb [d][s]
    unsigned short* sT = sAll;
#pragma unroll
    for (int m = 0; m < 2; m++)
#pragma unroll
      for (int j = 0; j < 4; j++) {
        const int srow = wm + m * 16 + lg * 4 + j;
#pragma unroll
        for (int n = 0; n < 4; n++)
          sT[(hsel * 64 + srow) * 72 + n * 16 + lr] = f2bf(acc[m][n][j]);
      }
    __syncthreads();
    const int hd = t >> 7;                 // head within block: 0/1
    const int d  = (t >> 1) & 63;
    const int sh = t & 1;                  // s-half: 0/1
    const int hk = 2 * (bn - 10) + hd;
    unsigned short* dst = vtb + ((size_t)((bb * 4 + hk) * 64 + d)) * 2048 +
                          (int)(m0 & 2047) + sh * 32;
    ushort8 o;
#pragma unroll
    for (int c = 0; c < 4; ++c) {
#pragma unroll
      for (int k = 0; k < 8; ++k) o[k] = sT[(hd * 64 + sh * 32 + c * 8 + k) * 72 + d];
      *(ushort8*)(dst + c * 8) = o;
    }
  }
}

// ---------------- bf16 GEMM: C[M,N] f32 = A[M,K] * B[N,K]^T (out proj) ----------------
__global__ __launch_bounds__(256) void gemm_bt_kernel(
    const unsigned short* __restrict__ A, const unsigned short* __restrict__ B,
    float* __restrict__ C, int M, int N, int K, int nbn) {
  __shared__ unsigned short sA[64 * 64];
  __shared__ unsigned short sB[128 * 64];
  const int t = threadIdx.x;
  const int lane = t & 63;
  const int w = t >> 6;
  const int bm = blockIdx.x / nbn, bn = blockIdx.x % nbn;
  const long m0 = (long)bm * 64, n0 = (long)bn * 128;
  const int wm = (w >> 1) * 32, wn = (w & 1) * 64;
  const int lr = lane & 15, lg = lane >> 4;
  f32x4 acc[2][4];
#pragma unroll
  for (int i = 0; i < 2; i++)
#pragma unroll
    for (int j = 0; j < 4; j++) acc[i][j] = (f32x4){0.f, 0.f, 0.f, 0.f};

  for (int k0 = 0; k0 < K; k0 += 64) {
#pragma unroll
    for (int i = 0; i < 2; i++) {
      int chunk = i * 256 + t;
      int r = chunk >> 3;
      int c = (chunk & 7) << 3;
      gload16(A + (m0 + r) * (long)K + k0 + c, (char*)sA + chunk * 16);
    }
#pragma unroll
    for (int i = 0; i < 4; i++) {
      int chunk = i * 256 + t;
      int r = chunk >> 3;
      int c = (chunk & 7) << 3;
      gload16(B + (n0 + r) * (long)K + k0 + c, (char*)sB + chunk * 16);
    }
    __syncthreads();
#pragma unroll
    for (int kk = 0; kk < 2; ++kk) {
      bf16x8 af[2], bfr[4];
#pragma unroll
      for (int m = 0; m < 2; m++)
        af[m] = *(const bf16x8*)&sA[(wm + m * 16 + lr) * 64 + kk * 32 + lg * 8];
#pragma unroll
      for (int n = 0; n < 4; n++)
        bfr[n] = *(const bf16x8*)&sB[(wn + n * 16 + lr) * 64 + kk * 32 + lg * 8];
#pragma unroll
      for (int m = 0; m < 2; m++)
#pragma unroll
        for (int n = 0; n < 4; n++)
          acc[m][n] = __builtin_amdgcn_mfma_f32_16x16x32_bf16(af[m], bfr[n], acc[m][n], 0, 0, 0);
    }
    __syncthreads();
  }
#pragma unroll
  for (int m = 0; m < 2; m++) {
#pragma unroll
    for (int n = 0; n < 4; n++) {
      long col = n0 + wn + n * 16 + lr;
#pragma unroll
      for (int j = 0; j < 4; j++) {
        long row = m0 + wm + m * 16 + lg * 4 + j;
        C[row * N + col] = acc[m][n][j];
      }
    }
  }
}

// ---------------- causal flash attention: KVBLK=128 (fixed-cost amortization) ----------
// 4 waves / 256 threads; block = 64 q rows of one (b,h). K[128][64] + V^T[64][128]
// double-buffered (64KB LDS): barriers/drains per kv halve vs KVBLK=64. Same per-kv
// LDS traffic and swizzles (involutions verified). Fixed-max softmax (-M in MFMA C),
// raw v_exp_f32 (exp(-1e30)=0 keeps fully-masked columns exact), balanced qt pairing.
__global__ __launch_bounds__(256) void attn_kernel(
    const unsigned short* __restrict__ qb, const unsigned short* __restrict__ kb,
    const unsigned short* __restrict__ vtb, unsigned short* __restrict__ yb,
    const float* __restrict__ qg) {
  __shared__ unsigned short sK[2][128 * 64];
  __shared__ unsigned short sV[2][64 * 128];
  const int tid = threadIdx.x;
  const int lane = tid & 63;
  const int w = tid >> 6;
  const int u = blockIdx.x >> 5;
  const int qt = (u < 16) ? (31 - u) : (u - 16);   // balanced pairing, heavy early
  const int bh = blockIdx.x & 31;
  const int h = bh & 15;
  const int b = bh >> 4;
  const float M = 11.7f * fabsf(qg[h]);
  const int q0 = qt * 64 + w * 16;
  const unsigned short* Q  = qb  + (size_t)(b * 16 + h) * 2048 * 64;
  const unsigned short* Kp = kb  + (size_t)(b * 4 + (h >> 2)) * 2048 * 64;
  const unsigned short* Vp = vtb + (size_t)(b * 4 + (h >> 2)) * 64 * 2048;
  const int qc = lane & 15;
  const int g = lane >> 4;
  const int qrow = q0 + qc;
  const bf16x8 qf0 = *(const bf16x8*)(Q + (size_t)qrow * 64 + g * 8);
  const bf16x8 qf1 = *(const bf16x8*)(Q + (size_t)qrow * 64 + 32 + g * 8);
  const f32x4 negM = (f32x4){-M, -M, -M, -M};
  f32x4 acc[4];
  acc[0] = acc[1] = acc[2] = acc[3] = (f32x4){0.f, 0.f, 0.f, 0.f};
  float lsum = 0.f;
  const int nt = (qt >> 1) + 1;            // 128-kv tiles

  // K staging: rows r0+32i (i=0..3); (r&7) invariant under +32
  const int r0 = tid >> 3, c0 = tid & 7;
  const int swzK = ((c0 ^ (r0 & 7)) << 3);
  const unsigned short* gK = Kp + (size_t)r0 * 64 + swzK;
  // V staging: rows rv+16i (i=0..3), 16 col-chunks; (r&7) invariant under +16
  const int rv = tid >> 4, cv = tid & 15;
  const int swzV = ((cv ^ (rv & 7)) << 3);
  const unsigned short* gV = Vp + (size_t)rv * 2048 + swzV;

#pragma unroll
  for (int i = 0; i < 4; ++i)
    gload16(gK + i * 32 * 64, (char*)&sK[0][0] + (tid + 256 * i) * 16);
#pragma unroll
  for (int i = 0; i < 4; ++i)
    gload16(gV + i * 16 * 2048, (char*)&sV[0][0] + (tid + 256 * i) * 16);
  gK += 128 * 64; gV += 128;

  int cur = 0;
  for (int t = 0; t < nt; ++t) {
    __syncthreads();   // drains vmcnt: buf[cur] staged; buf[cur^1] free
    if (t + 1 < nt) {  // prefetch next tile
      const int nb = cur ^ 1;
#pragma unroll
      for (int i = 0; i < 4; ++i)
        gload16(gK + i * 32 * 64, (char*)&sK[nb][0] + (tid + 256 * i) * 16);
#pragma unroll
      for (int i = 0; i < 4; ++i)
        gload16(gV + i * 16 * 2048, (char*)&sV[nb][0] + (tid + 256 * i) * 16);
      gK += 128 * 64; gV += 128;
    }
    const unsigned short* sKc = &sK[cur][0];
    const unsigned short* sVc = &sV[cur][0];
    // ---- QK^T: 8 sub-tiles of 16 kv (C-in = -M) ----
    f32x4 st[8];
    __builtin_amdgcn_s_setprio(1);
#pragma unroll
    for (int ks = 0; ks < 8; ++ks) {
      const int rr = ks * 16 + qc;
      bf16x8 kf0 = *(const bf16x8*)&sKc[rr * 64 + ((g ^ (rr & 7)) << 3)];
      bf16x8 kf1 = *(const bf16x8*)&sKc[rr * 64 + (((4 + g) ^ (rr & 7)) << 3)];
      f32x4 a = negM;
      a = __builtin_amdgcn_mfma_f32_16x16x32_bf16(kf0, qf0, a, 0, 0, 0);
      a = __builtin_amdgcn_mfma_f32_16x16x32_bf16(kf1, qf1, a, 0, 0, 0);
      st[ks] = a;
    }
    __builtin_amdgcn_s_setprio(0);
    if (t == nt - 1) {  // last tile: global causal mask
#pragma unroll
      for (int ks = 0; ks < 8; ++ks)
#pragma unroll
        for (int j = 0; j < 4; ++j)
          if ((t << 7) + ks * 16 + g * 4 + j > qrow) st[ks][j] = -1e30f;
    }
    // ---- fixed-max softmax: p = v_exp_f32(st) ----
    short4v pb[8];
#pragma unroll
    for (int ks = 0; ks < 8; ++ks)
#pragma unroll
      for (int j = 0; j < 4; ++j) {
        float p = EXP2(st[ks][j]);
        lsum += p;
        pb[ks][j] = bfbits(p);
      }
    // ---- PV: Y^T += V^T * P^T ----
    __builtin_amdgcn_s_setprio(1);
#pragma unroll
    for (int ks = 0; ks < 8; ++ks) {
#pragma unroll
      for (int d = 0; d < 4; ++d) {
        const int rd = d * 16 + qc;
        const int el = rd * 128 + ((((ks * 2 + (g >> 1)) ^ (rd & 7)) << 3) + ((g & 1) << 2));
        short4v vf = *(const short4v*)&sVc[el];
        acc[d] = __builtin_amdgcn_mfma_f32_16x16x16bf16_1k(vf, pb[ks], acc[d], 0, 0, 0);
      }
    }
    __builtin_amdgcn_s_setprio(0);
    cur ^= 1;
  }
  float l = lsum;
  l += __shfl_xor(l, 16);
  l += __shfl_xor(l, 32);
  const float inv = 1.0f / l;
  unsigned short* Y = yb + (size_t)(b * 2048 + qrow) * 1024 + h * 64;
#pragma unroll
  for (int d = 0; d < 4; ++d) {
    ushort4v o;
#pragma unroll
    for (int j = 0; j < 4; ++j) o[j] = (unsigned short)bfbits(acc[d][j] * inv);
    *(ushort4v*)(Y + d * 16 + g * 4) = o;
  }
}

extern "C" void kernel_launch(void* const* d_in, const int* in_sizes, int n_in,
                              void* d_out, int out_size, void* d_ws, size_t ws_size,
                              hipStream_t stream) {
  const float* x  = (const float*)d_in[0];
  const float* Wq = (const float*)d_in[1];
  const float* Wk = (const float*)d_in[2];
  const float* Wv = (const float*)d_in[3];
  const float* Wo = (const float*)d_in[4];
  const float* qg = (const float*)d_in[5];
  float* out = (float*)d_out;

  char* ws = (char*)d_ws;
  const size_t NEED = 35127296;
  if (ws_size < NEED) return;
  unsigned short* xb   = (unsigned short*)(ws);                 // 8,388,608
  unsigned short* wqkv = (unsigned short*)(ws + 8388608);       // 3,145,728
  unsigned short* wo_b = (unsigned short*)(ws + 11534336);      // 2,097,152
  unsigned short* qbuf = (unsigned short*)(ws + 13631488);      // 8,388,608
  unsigned short* kbuf = (unsigned short*)(ws + 22020096);      // 2,097,152
  unsigned short* vtb  = (unsigned short*)(ws + 24117248);      // 2,097,152
  unsigned short* ybuf = (unsigned short*)(ws + 26214400);      // 8,388,608
  float*          tab  = (float*)        (ws + 34603008);       // 524,288

  prep_kernel<<<6912, 256, 0, stream>>>(x, Wq, Wk, Wv, Wo, xb, wqkv, wo_b, tab);
  gemm_qkv_kernel<<<64 * 12, 256, 0, stream>>>(xb, wqkv, tab, qg, qbuf, kbuf, vtb);
  attn_kernel<<<1024, 256, 0, stream>>>(qbuf, kbuf, vtb, ybuf, qg);
  gemm_bt_kernel<<<64 * 8, 256, 0, stream>>>(ybuf, wo_b, out, 4096, 1024, 1024, 8);
}

// Round 20
// 99.387 us; speedup vs baseline: 1.1036x; 1.1036x over previous
//
#include <hip/hip_runtime.h>
#include <hip/hip_bf16.h>
#include <math.h>

typedef __attribute__((ext_vector_type(8))) __bf16 bf16x8;
typedef __attribute__((ext_vector_type(4))) short short4v;
typedef __attribute__((ext_vector_type(4))) float f32x4;
typedef __attribute__((ext_vector_type(4))) unsigned short ushort4v;
typedef __attribute__((ext_vector_type(8))) unsigned short ushort8;

#define LOG2E 1.44269504088896340736f

extern "C" __device__ float __ocml_native_exp2_f32(float);
#if __has_builtin(__builtin_amdgcn_exp2f)
#define EXP2(x) __builtin_amdgcn_exp2f(x)
#else
#define EXP2(x) __ocml_native_exp2_f32(x)
#endif

static __device__ __forceinline__ unsigned short f2bf(float f) {
  unsigned int u = __float_as_uint(f);
  return (unsigned short)((u + 0x7fffu + ((u >> 16) & 1u)) >> 16);
}
static __device__ __forceinline__ short bfbits(float f) {
  __bf16 h = (__bf16)f;
  return __builtin_bit_cast(short, h);
}

static __device__ __forceinline__ void gload16(const unsigned short* g, void* l) {
  __builtin_amdgcn_global_load_lds(
      (const __attribute__((address_space(1))) unsigned int*)g,
      (__attribute__((address_space(3))) unsigned int*)l, 16, 0, 0);
}

// ---------------- fused prep: all casts + RoPE table ----------------
__global__ __launch_bounds__(256) void prep_kernel(
    const float* __restrict__ x, const float* __restrict__ Wq,
    const float* __restrict__ Wk, const float* __restrict__ Wv,
    const float* __restrict__ Wo,
    unsigned short* __restrict__ xb, unsigned short* __restrict__ wqkv,
    unsigned short* __restrict__ wo_b, float* __restrict__ tab) {
  const int bx = blockIdx.x, tid = threadIdx.x;
  if (bx < 6656) {
    const float* src;
    unsigned short* dst;
    int i;
    if (bx < 4096)       { src = x;  dst = xb;             i = bx * 256 + tid; }
    else if (bx < 5120)  { src = Wq; dst = wqkv;           i = (bx - 4096) * 256 + tid; }
    else if (bx < 5376)  { src = Wk; dst = wqkv + 1048576; i = (bx - 5120) * 256 + tid; }
    else if (bx < 5632)  { src = Wv; dst = wqkv + 1310720; i = (bx - 5376) * 256 + tid; }
    else                 { src = Wo; dst = wo_b;           i = (bx - 5632) * 256 + tid; }
    float4 v = reinterpret_cast<const float4*>(src)[i];
    ushort4v o;
    o.x = f2bf(v.x); o.y = f2bf(v.y); o.z = f2bf(v.z); o.w = f2bf(v.w);
    reinterpret_cast<ushort4v*>(dst)[i] = o;
  } else {
    int i = (bx - 6656) * 256 + tid;  // 65536 = 2048*32
    int s = i >> 5, d = i & 31;
    float invf = powf(10000.f, -(float)d / 32.f);
    float fr = (float)s * invf;
    tab[s * 64 + d] = cosf(fr);
    tab[s * 64 + 32 + d] = sinf(fr);
  }
}

// ---------------- fused QKV GEMM: qkv = x @ Wqkv^T + RMSNorm/RoPE/pack epilogue ----
// BM=64, BN=128, BK=64; 4 waves (2x2), wave tile 32x64 = acc[2][4].
// Single-barrier double-buffered staging (prefetch k+1 overlaps compute k).
// Q/K (bn<10): RMSNorm + RoPE + gain -> bf16. V (bn 10,11): bf16 + in-LDS transpose.
__global__ __launch_bounds__(256) void gemm_qkv_kernel(
    const unsigned short* __restrict__ A, const unsigned short* __restrict__ B,
    const float* __restrict__ tab, const float* __restrict__ qg,
    unsigned short* __restrict__ qb, unsigned short* __restrict__ kb,
    unsigned short* __restrict__ vtb) {
  __shared__ unsigned short sAll[2 * 64 * 64 + 2 * 128 * 64];
  unsigned short* sA = sAll;                  // [2][64*64]
  unsigned short* sB = sAll + 2 * 64 * 64;    // [2][128*64]
  const int t = threadIdx.x;
  const int lane = t & 63;
  const int w = t >> 6;
  const int bm = blockIdx.x / 12, bn = blockIdx.x % 12;
  const long m0 = (long)bm * 64, n0 = (long)bn * 128;
  const int wm = (w >> 1) * 32, wn = (w & 1) * 64;
  const int lr = lane & 15, lg = lane >> 4;
  f32x4 acc[2][4];
#pragma unroll
  for (int i = 0; i < 2; i++)
#pragma unroll
    for (int j = 0; j < 4; j++) acc[i][j] = (f32x4){0.f, 0.f, 0.f, 0.f};

#define STAGE_QKV(bufi, kk0)                                                            \
  do {                                                                                  \
    _Pragma("unroll")                                                                   \
    for (int i = 0; i < 2; i++) {                                                       \
      int chunk = i * 256 + t;                                                          \
      int r = chunk >> 3;                                                               \
      int c = (chunk & 7) << 3;                                                         \
      gload16(A + (m0 + r) * 1024 + (kk0) + c, (char*)(sA + (bufi) * 4096) + chunk * 16); \
    }                                                                                   \
    _Pragma("unroll")                                                                   \
    for (int i = 0; i < 4; i++) {                                                       \
      int chunk = i * 256 + t;                                                          \
      int r = chunk >> 3;                                                               \
      int c = (chunk & 7) << 3;                                                         \
      gload16(B + (n0 + r) * 1024 + (kk0) + c, (char*)(sB + (bufi) * 8192) + chunk * 16); \
    }                                                                                   \
  } while (0)

  STAGE_QKV(0, 0);
  int cur = 0;
  for (int k0 = 0; k0 < 1024; k0 += 64) {
    __syncthreads();   // prefetched buf[cur] staged; prior compute (buf[cur^1]) done
    if (k0 + 64 < 1024) STAGE_QKV(cur ^ 1, k0 + 64);
    const unsigned short* cA = sA + cur * 4096;
    const unsigned short* cB = sB + cur * 8192;
#pragma unroll
    for (int kk = 0; kk < 2; ++kk) {
      bf16x8 af[2], bfr[4];
#pragma unroll
      for (int m = 0; m < 2; m++)
        af[m] = *(const bf16x8*)&cA[(wm + m * 16 + lr) * 64 + kk * 32 + lg * 8];
#pragma unroll
      for (int n = 0; n < 4; n++)
        bfr[n] = *(const bf16x8*)&cB[(wn + n * 16 + lr) * 64 + kk * 32 + lg * 8];
#pragma unroll
      for (int m = 0; m < 2; m++)
#pragma unroll
        for (int n = 0; n < 4; n++)
          acc[m][n] = __builtin_amdgcn_mfma_f32_16x16x32_bf16(af[m], bfr[n], acc[m][n], 0, 0, 0);
    }
    cur ^= 1;
  }
#undef STAGE_QKV
  __syncthreads();   // all LDS reads done before epilogue reuses sAll
  // ---- fused epilogue ----
  const int bb = (int)(m0 >> 11);          // batch (64-row tile never straddles b)
  const int s_base = (int)(m0 & 2047) + wm + lg * 4;
  const int hsel = wn >> 6;                // which head of the 128-col block
  if (bn < 10) {
    float gscale = 1.0f;
    unsigned short* dstb;
    if (bn < 8) {
      gscale = qg[2 * bn + hsel] * (0.125f * LOG2E);
      dstb = qb + (size_t)(bb * 16 + 2 * bn + hsel) * 2048 * 64;
    } else {
      dstb = kb + (size_t)(bb * 4 + 2 * (bn - 8) + hsel) * 2048 * 64;
    }
#pragma unroll
    for (int m = 0; m < 2; m++) {
#pragma unroll
      for (int j = 0; j < 4; j++) {
        float ss = acc[m][0][j] * acc[m][0][j] + acc[m][1][j] * acc[m][1][j] +
                   acc[m][2][j] * acc[m][2][j] + acc[m][3][j] * acc[m][3][j];
        ss += __shfl_xor(ss, 1);
        ss += __shfl_xor(ss, 2);
        ss += __shfl_xor(ss, 4);
        ss += __shfl_xor(ss, 8);
        const float rinv = rsqrtf(ss * (1.0f / 64.0f) + 1.1920929e-07f);
        const int s = s_base + m * 16 + j;
        const float* tr = tab + s * 64;
        const float c0 = tr[lr], c1 = tr[16 + lr];
        const float s0 = tr[32 + lr], s1 = tr[48 + lr];
        const float n0v = acc[m][0][j] * rinv, n1v = acc[m][1][j] * rinv;
        const float n2v = acc[m][2][j] * rinv, n3v = acc[m][3][j] * rinv;
        float o0 = (n0v * c0 + n2v * s0) * gscale;
        float o1 = (n1v * c1 + n3v * s1) * gscale;
        float o2 = (n2v * c0 - n0v * s0) * gscale;
        float o3 = (n3v * c1 - n1v * s1) * gscale;
        unsigned short* d = dstb + (size_t)s * 64;
        d[lr]      = f2bf(o0);
        d[16 + lr] = f2bf(o1);
        d[32 + lr] = f2bf(o2);
        d[48 + lr] = f2bf(o3);
      }
    }
  } else {
    // V (bn 10,11): bf16 + transpose via LDS [2 heads][64 s][72 pad] -> vtb [d][s]
    unsigned short* sT = sAll;
#pragma unroll
    for (int m = 0; m < 2; m++)
#pragma unroll
      for (int j = 0; j < 4; j++) {
        const int srow = wm + m * 16 + lg * 4 + j;
#pragma unroll
        for (int n = 0; n < 4; n++)
          sT[(hsel * 64 + srow) * 72 + n * 16 + lr] = f2bf(acc[m][n][j]);
      }
    __syncthreads();
    const int hd = t >> 7;                 // head within block: 0/1
    const int d  = (t >> 1) & 63;
    const int sh = t & 1;                  // s-half: 0/1
    const int hk = 2 * (bn - 10) + hd;
    unsigned short* dst = vtb + ((size_t)((bb * 4 + hk) * 64 + d)) * 2048 +
                          (int)(m0 & 2047) + sh * 32;
    ushort8 o;
#pragma unroll
    for (int c = 0; c < 4; ++c) {
#pragma unroll
      for (int k = 0; k < 8; ++k) o[k] = sT[(hd * 64 + sh * 32 + c * 8 + k) * 72 + d];
      *(ushort8*)(dst + c * 8) = o;
    }
  }
}

// ---------------- bf16 GEMM: C[M,N] f32 = A[M,K] * B[N,K]^T (out proj) ----------------
// Single-barrier double-buffered staging.
__global__ __launch_bounds__(256) void gemm_bt_kernel(
    const unsigned short* __restrict__ A, const unsigned short* __restrict__ B,
    float* __restrict__ C, int M, int N, int K, int nbn) {
  __shared__ unsigned short sA[2][64 * 64];
  __shared__ unsigned short sB[2][128 * 64];
  const int t = threadIdx.x;
  const int lane = t & 63;
  const int w = t >> 6;
  const int bm = blockIdx.x / nbn, bn = blockIdx.x % nbn;
  const long m0 = (long)bm * 64, n0 = (long)bn * 128;
  const int wm = (w >> 1) * 32, wn = (w & 1) * 64;
  const int lr = lane & 15, lg = lane >> 4;
  f32x4 acc[2][4];
#pragma unroll
  for (int i = 0; i < 2; i++)
#pragma unroll
    for (int j = 0; j < 4; j++) acc[i][j] = (f32x4){0.f, 0.f, 0.f, 0.f};

#define STAGE_BT(bufi, kk0)                                                             \
  do {                                                                                  \
    _Pragma("unroll")                                                                   \
    for (int i = 0; i < 2; i++) {                                                       \
      int chunk = i * 256 + t;                                                          \
      int r = chunk >> 3;                                                               \
      int c = (chunk & 7) << 3;                                                         \
      gload16(A + (m0 + r) * (long)K + (kk0) + c, (char*)&sA[bufi][0] + chunk * 16);    \
    }                                                                                   \
    _Pragma("unroll")                                                                   \
    for (int i = 0; i < 4; i++) {                                                       \
      int chunk = i * 256 + t;                                                          \
      int r = chunk >> 3;                                                               \
      int c = (chunk & 7) << 3;                                                         \
      gload16(B + (n0 + r) * (long)K + (kk0) + c, (char*)&sB[bufi][0] + chunk * 16);    \
    }                                                                                   \
  } while (0)

  STAGE_BT(0, 0);
  int cur = 0;
  for (int k0 = 0; k0 < K; k0 += 64) {
    __syncthreads();   // prefetched buf[cur] staged; prior compute done
    if (k0 + 64 < K) STAGE_BT(cur ^ 1, k0 + 64);
    const unsigned short* cA = &sA[cur][0];
    const unsigned short* cB = &sB[cur][0];
#pragma unroll
    for (int kk = 0; kk < 2; ++kk) {
      bf16x8 af[2], bfr[4];
#pragma unroll
      for (int m = 0; m < 2; m++)
        af[m] = *(const bf16x8*)&cA[(wm + m * 16 + lr) * 64 + kk * 32 + lg * 8];
#pragma unroll
      for (int n = 0; n < 4; n++)
        bfr[n] = *(const bf16x8*)&cB[(wn + n * 16 + lr) * 64 + kk * 32 + lg * 8];
#pragma unroll
      for (int m = 0; m < 2; m++)
#pragma unroll
        for (int n = 0; n < 4; n++)
          acc[m][n] = __builtin_amdgcn_mfma_f32_16x16x32_bf16(af[m], bfr[n], acc[m][n], 0, 0, 0);
    }
    cur ^= 1;
  }
#undef STAGE_BT
#pragma unroll
  for (int m = 0; m < 2; m++) {
#pragma unroll
    for (int n = 0; n < 4; n++) {
      long col = n0 + wn + n * 16 + lr;
#pragma unroll
      for (int j = 0; j < 4; j++) {
        long row = m0 + wm + m * 16 + lg * 4 + j;
        C[row * N + col] = acc[m][n][j];
      }
    }
  }
}

// ---------------- causal flash attention (measured-best: R15/R18) ----------------
// 4 waves / 256 threads; block = 64 q rows of one (b,h); KVBLK=64, K+V double-buffered
// LDS (32KB, multicast to all 4 waves). Fixed-max softmax (-M in MFMA C), raw v_exp_f32,
// balanced heavy-early qt pairing, hoisted staging pointers.
__global__ __launch_bounds__(256) void attn_kernel(
    const unsigned short* __restrict__ qb, const unsigned short* __restrict__ kb,
    const unsigned short* __restrict__ vtb, unsigned short* __restrict__ yb,
    const float* __restrict__ qg) {
  __shared__ unsigned short sK[2][64 * 64];
  __shared__ unsigned short sV[2][64 * 64];
  const int tid = threadIdx.x;
  const int lane = tid & 63;
  const int w = tid >> 6;
  const int u = blockIdx.x >> 5;
  const int qt = (u < 16) ? (31 - u) : (u - 16);   // balanced pairing, heavy early
  const int bh = blockIdx.x & 31;
  const int h = bh & 15;
  const int b = bh >> 4;
  const float M = 11.7f * fabsf(qg[h]);
  const int q0 = qt * 64 + w * 16;
  const unsigned short* Q  = qb  + (size_t)(b * 16 + h) * 2048 * 64;
  const unsigned short* Kp = kb  + (size_t)(b * 4 + (h >> 2)) * 2048 * 64;
  const unsigned short* Vp = vtb + (size_t)(b * 4 + (h >> 2)) * 64 * 2048;
  const int qc = lane & 15;
  const int g = lane >> 4;
  const int qrow = q0 + qc;
  const bf16x8 qf0 = *(const bf16x8*)(Q + (size_t)qrow * 64 + g * 8);
  const bf16x8 qf1 = *(const bf16x8*)(Q + (size_t)qrow * 64 + 32 + g * 8);
  const f32x4 negM = (f32x4){-M, -M, -M, -M};
  f32x4 acc[4];
  acc[0] = acc[1] = acc[2] = acc[3] = (f32x4){0.f, 0.f, 0.f, 0.f};
  float lsum = 0.f;
  const int nt = qt + 1;

  // hoisted staging pointers: 2 K-chunks + 2 V-chunks per thread
  const int r0 = tid >> 3, c0 = tid & 7;
  const int swz = ((c0 ^ (r0 & 7)) << 3);
  const unsigned short* gK = Kp + (size_t)r0 * 64 + swz;
  const unsigned short* gV = Vp + (size_t)r0 * 2048 + swz;

  gload16(gK,             (char*)&sK[0][0] + tid * 16);
  gload16(gK + 32 * 64,   (char*)&sK[0][0] + (tid + 256) * 16);
  gload16(gV,             (char*)&sV[0][0] + tid * 16);
  gload16(gV + 32 * 2048, (char*)&sV[0][0] + (tid + 256) * 16);
  gK += 64 * 64; gV += 64;

  int cur = 0;
  for (int t = 0; t < nt; ++t) {
    __syncthreads();   // drains vmcnt: buf[cur] staged; buf[cur^1] free
    if (t + 1 < nt) {  // prefetch next tile
      const int nb = cur ^ 1;
      gload16(gK,             (char*)&sK[nb][0] + tid * 16);
      gload16(gK + 32 * 64,   (char*)&sK[nb][0] + (tid + 256) * 16);
      gload16(gV,             (char*)&sV[nb][0] + tid * 16);
      gload16(gV + 32 * 2048, (char*)&sV[nb][0] + (tid + 256) * 16);
      gK += 64 * 64; gV += 64;
    }
    const unsigned short* sKc = &sK[cur][0];
    const unsigned short* sVc = &sV[cur][0];
    // ---- QK^T (C-in = -M: scores come out pre-shifted) ----
    f32x4 st[4];
    __builtin_amdgcn_s_setprio(1);
#pragma unroll
    for (int ks = 0; ks < 4; ++ks) {
      const int rr = ks * 16 + qc;
      bf16x8 kf0 = *(const bf16x8*)&sKc[rr * 64 + ((g ^ (rr & 7)) << 3)];
      bf16x8 kf1 = *(const bf16x8*)&sKc[rr * 64 + (((4 + g) ^ (rr & 7)) << 3)];
      f32x4 a = negM;
      a = __builtin_amdgcn_mfma_f32_16x16x32_bf16(kf0, qf0, a, 0, 0, 0);
      a = __builtin_amdgcn_mfma_f32_16x16x32_bf16(kf1, qf1, a, 0, 0, 0);
      st[ks] = a;
    }
    __builtin_amdgcn_s_setprio(0);
    if (t == nt - 1) {  // diagonal tile: within-tile causal mask
#pragma unroll
      for (int ks = 0; ks < 4; ++ks)
#pragma unroll
        for (int j = 0; j < 4; ++j)
          if (ks * 16 + g * 4 + j > w * 16 + qc) st[ks][j] = -1e30f;
    }
    // ---- fixed-max softmax: p = v_exp_f32(st), one instr/score ----
    short4v pb[4];
#pragma unroll
    for (int ks = 0; ks < 4; ++ks)
#pragma unroll
      for (int j = 0; j < 4; ++j) {
        float p = EXP2(st[ks][j]);
        lsum += p;
        pb[ks][j] = bfbits(p);
      }
    // ---- PV: Y^T += V^T * P^T ----
    __builtin_amdgcn_s_setprio(1);
#pragma unroll
    for (int ks = 0; ks < 4; ++ks) {
#pragma unroll
      for (int d = 0; d < 4; ++d) {
        const int rd = d * 16 + qc;
        const int el = rd * 64 + ((((ks * 2 + (g >> 1)) ^ (rd & 7)) << 3) + ((g & 1) << 2));
        short4v vf = *(const short4v*)&sVc[el];
        acc[d] = __builtin_amdgcn_mfma_f32_16x16x16bf16_1k(vf, pb[ks], acc[d], 0, 0, 0);
      }
    }
    __builtin_amdgcn_s_setprio(0);
    cur ^= 1;
  }
  float l = lsum;
  l += __shfl_xor(l, 16);
  l += __shfl_xor(l, 32);
  const float inv = 1.0f / l;
  unsigned short* Y = yb + (size_t)(b * 2048 + qrow) * 1024 + h * 64;
#pragma unroll
  for (int d = 0; d < 4; ++d) {
    ushort4v o;
#pragma unroll
    for (int j = 0; j < 4; ++j) o[j] = (unsigned short)bfbits(acc[d][j] * inv);
    *(ushort4v*)(Y + d * 16 + g * 4) = o;
  }
}

extern "C" void kernel_launch(void* const* d_in, const int* in_sizes, int n_in,
                              void* d_out, int out_size, void* d_ws, size_t ws_size,
                              hipStream_t stream) {
  const float* x  = (const float*)d_in[0];
  const float* Wq = (const float*)d_in[1];
  const float* Wk = (const float*)d_in[2];
  const float* Wv = (const float*)d_in[3];
  const float* Wo = (const float*)d_in[4];
  const float* qg = (const float*)d_in[5];
  float* out = (float*)d_out;

  char* ws = (char*)d_ws;
  const size_t NEED = 35127296;
  if (ws_size < NEED) return;
  unsigned short* xb   = (unsigned short*)(ws);                 // 8,388,608
  unsigned short* wqkv = (unsigned short*)(ws + 8388608);       // 3,145,728
  unsigned short* wo_b = (unsigned short*)(ws + 11534336);      // 2,097,152
  unsigned short* qbuf = (unsigned short*)(ws + 13631488);      // 8,388,608
  unsigned short* kbuf = (unsigned short*)(ws + 22020096);      // 2,097,152
  unsigned short* vtb  = (unsigned short*)(ws + 24117248);      // 2,097,152
  unsigned short* ybuf = (unsigned short*)(ws + 26214400);      // 8,388,608
  float*          tab  = (float*)        (ws + 34603008);       // 524,288

  prep_kernel<<<6912, 256, 0, stream>>>(x, Wq, Wk, Wv, Wo, xb, wqkv, wo_b, tab);
  gemm_qkv_kernel<<<64 * 12, 256, 0, stream>>>(xb, wqkv, tab, qg, qbuf, kbuf, vtb);
  attn_kernel<<<1024, 256, 0, stream>>>(qbuf, kbuf, vtb, ybuf, qg);
  gemm_bt_kernel<<<64 * 8, 256, 0, stream>>>(ybuf, wo_b, out, 4096, 1024, 1024, 8);
}

// Round 21
// 98.087 us; speedup vs baseline: 1.1183x; 1.0133x over previous
//
#include <hip/hip_runtime.h>
#include <hip/hip_bf16.h>
#include <math.h>

typedef __attribute__((ext_vector_type(8))) __bf16 bf16x8;
typedef __attribute__((ext_vector_type(4))) short short4v;
typedef __attribute__((ext_vector_type(4))) float f32x4;
typedef __attribute__((ext_vector_type(4))) unsigned short ushort4v;
typedef __attribute__((ext_vector_type(8))) unsigned short ushort8;

#define LOG2E 1.44269504088896340736f

extern "C" __device__ float __ocml_native_exp2_f32(float);
#if __has_builtin(__builtin_amdgcn_exp2f)
#define EXP2(x) __builtin_amdgcn_exp2f(x)
#else
#define EXP2(x) __ocml_native_exp2_f32(x)
#endif

static __device__ __forceinline__ unsigned short f2bf(float f) {
  unsigned int u = __float_as_uint(f);
  return (unsigned short)((u + 0x7fffu + ((u >> 16) & 1u)) >> 16);
}
static __device__ __forceinline__ short bfbits(float f) {
  __bf16 h = (__bf16)f;
  return __builtin_bit_cast(short, h);
}

static __device__ __forceinline__ void gload16(const unsigned short* g, void* l) {
  __builtin_amdgcn_global_load_lds(
      (const __attribute__((address_space(1))) unsigned int*)g,
      (__attribute__((address_space(3))) unsigned int*)l, 16, 0, 0);
}

// ---------------- fused prep: all casts + RoPE table (raw HW trig) ----------------
__global__ __launch_bounds__(256) void prep_kernel(
    const float* __restrict__ x, const float* __restrict__ Wq,
    const float* __restrict__ Wk, const float* __restrict__ Wv,
    const float* __restrict__ Wo,
    unsigned short* __restrict__ xb, unsigned short* __restrict__ wqkv,
    unsigned short* __restrict__ wo_b, float* __restrict__ tab) {
  const int bx = blockIdx.x, tid = threadIdx.x;
  if (bx < 6656) {
    const float* src;
    unsigned short* dst;
    int i;
    if (bx < 4096)       { src = x;  dst = xb;             i = bx * 256 + tid; }
    else if (bx < 5120)  { src = Wq; dst = wqkv;           i = (bx - 4096) * 256 + tid; }
    else if (bx < 5376)  { src = Wk; dst = wqkv + 1048576; i = (bx - 5120) * 256 + tid; }
    else if (bx < 5632)  { src = Wv; dst = wqkv + 1310720; i = (bx - 5376) * 256 + tid; }
    else                 { src = Wo; dst = wo_b;           i = (bx - 5632) * 256 + tid; }
    float4 v = reinterpret_cast<const float4*>(src)[i];
    ushort4v o;
    o.x = f2bf(v.x); o.y = f2bf(v.y); o.z = f2bf(v.z); o.w = f2bf(v.w);
    reinterpret_cast<ushort4v*>(dst)[i] = o;
  } else {
    int i = (bx - 6656) * 256 + tid;  // 65536 = 2048*32
    int s = i >> 5, d = i & 31;
    // invf = 10000^(-d/32) = exp2(d * -log2(10000)/32)  (one v_exp_f32)
    float invf = EXP2((float)d * -0.41524100371116434f);
    // v_sin/v_cos take revolutions: rev = fract(s*invf / 2pi)
    float rev = (float)s * invf * 0.15915494309189535f;
    rev = rev - floorf(rev);
#if __has_builtin(__builtin_amdgcn_cosf)
    tab[s * 64 + d]      = __builtin_amdgcn_cosf(rev);
    tab[s * 64 + 32 + d] = __builtin_amdgcn_sinf(rev);
#else
    tab[s * 64 + d]      = cosf(rev * 6.283185307179586f);
    tab[s * 64 + 32 + d] = sinf(rev * 6.283185307179586f);
#endif
  }
}

// ---------------- fused QKV GEMM: qkv = x @ Wqkv^T + RMSNorm/RoPE/pack epilogue ----
// BM=64, BN=128, BK=64; 4 waves (2x2), wave tile 32x64 = acc[2][4].
// Single-barrier double-buffered staging (prefetch k+1 overlaps compute k).
// Q/K (bn<10): RMSNorm + RoPE + gain -> bf16. V (bn 10,11): bf16 + in-LDS transpose.
__global__ __launch_bounds__(256) void gemm_qkv_kernel(
    const unsigned short* __restrict__ A, const unsigned short* __restrict__ B,
    const float* __restrict__ tab, const float* __restrict__ qg,
    unsigned short* __restrict__ qb, unsigned short* __restrict__ kb,
    unsigned short* __restrict__ vtb) {
  __shared__ unsigned short sAll[2 * 64 * 64 + 2 * 128 * 64];
  unsigned short* sA = sAll;                  // [2][64*64]
  unsigned short* sB = sAll + 2 * 64 * 64;    // [2][128*64]
  const int t = threadIdx.x;
  const int lane = t & 63;
  const int w = t >> 6;
  const int bm = blockIdx.x / 12, bn = blockIdx.x % 12;
  const long m0 = (long)bm * 64, n0 = (long)bn * 128;
  const int wm = (w >> 1) * 32, wn = (w & 1) * 64;
  const int lr = lane & 15, lg = lane >> 4;
  f32x4 acc[2][4];
#pragma unroll
  for (int i = 0; i < 2; i++)
#pragma unroll
    for (int j = 0; j < 4; j++) acc[i][j] = (f32x4){0.f, 0.f, 0.f, 0.f};

#define STAGE_QKV(bufi, kk0)                                                            \
  do {                                                                                  \
    _Pragma("unroll")                                                                   \
    for (int i = 0; i < 2; i++) {                                                       \
      int chunk = i * 256 + t;                                                          \
      int r = chunk >> 3;                                                               \
      int c = (chunk & 7) << 3;                                                         \
      gload16(A + (m0 + r) * 1024 + (kk0) + c, (char*)(sA + (bufi) * 4096) + chunk * 16); \
    }                                                                                   \
    _Pragma("unroll")                                                                   \
    for (int i = 0; i < 4; i++) {                                                       \
      int chunk = i * 256 + t;                                                          \
      int r = chunk >> 3;                                                               \
      int c = (chunk & 7) << 3;                                                         \
      gload16(B + (n0 + r) * 1024 + (kk0) + c, (char*)(sB + (bufi) * 8192) + chunk * 16); \
    }                                                                                   \
  } while (0)

  STAGE_QKV(0, 0);
  int cur = 0;
  for (int k0 = 0; k0 < 1024; k0 += 64) {
    __syncthreads();   // prefetched buf[cur] staged; prior compute (buf[cur^1]) done
    if (k0 + 64 < 1024) STAGE_QKV(cur ^ 1, k0 + 64);
    const unsigned short* cA = sA + cur * 4096;
    const unsigned short* cB = sB + cur * 8192;
#pragma unroll
    for (int kk = 0; kk < 2; ++kk) {
      bf16x8 af[2], bfr[4];
#pragma unroll
      for (int m = 0; m < 2; m++)
        af[m] = *(const bf16x8*)&cA[(wm + m * 16 + lr) * 64 + kk * 32 + lg * 8];
#pragma unroll
      for (int n = 0; n < 4; n++)
        bfr[n] = *(const bf16x8*)&cB[(wn + n * 16 + lr) * 64 + kk * 32 + lg * 8];
#pragma unroll
      for (int m = 0; m < 2; m++)
#pragma unroll
        for (int n = 0; n < 4; n++)
          acc[m][n] = __builtin_amdgcn_mfma_f32_16x16x32_bf16(af[m], bfr[n], acc[m][n], 0, 0, 0);
    }
    cur ^= 1;
  }
#undef STAGE_QKV
  __syncthreads();   // all LDS reads done before epilogue reuses sAll
  // ---- fused epilogue ----
  const int bb = (int)(m0 >> 11);          // batch (64-row tile never straddles b)
  const int s_base = (int)(m0 & 2047) + wm + lg * 4;
  const int hsel = wn >> 6;                // which head of the 128-col block
  if (bn < 10) {
    float gscale = 1.0f;
    unsigned short* dstb;
    if (bn < 8) {
      gscale = qg[2 * bn + hsel] * (0.125f * LOG2E);
      dstb = qb + (size_t)(bb * 16 + 2 * bn + hsel) * 2048 * 64;
    } else {
      dstb = kb + (size_t)(bb * 4 + 2 * (bn - 8) + hsel) * 2048 * 64;
    }
#pragma unroll
    for (int m = 0; m < 2; m++) {
#pragma unroll
      for (int j = 0; j < 4; j++) {
        float ss = acc[m][0][j] * acc[m][0][j] + acc[m][1][j] * acc[m][1][j] +
                   acc[m][2][j] * acc[m][2][j] + acc[m][3][j] * acc[m][3][j];
        ss += __shfl_xor(ss, 1);
        ss += __shfl_xor(ss, 2);
        ss += __shfl_xor(ss, 4);
        ss += __shfl_xor(ss, 8);
        const float rinv = rsqrtf(ss * (1.0f / 64.0f) + 1.1920929e-07f);
        const int s = s_base + m * 16 + j;
        const float* tr = tab + s * 64;
        const float c0 = tr[lr], c1 = tr[16 + lr];
        const float s0 = tr[32 + lr], s1 = tr[48 + lr];
        const float n0v = acc[m][0][j] * rinv, n1v = acc[m][1][j] * rinv;
        const float n2v = acc[m][2][j] * rinv, n3v = acc[m][3][j] * rinv;
        float o0 = (n0v * c0 + n2v * s0) * gscale;
        float o1 = (n1v * c1 + n3v * s1) * gscale;
        float o2 = (n2v * c0 - n0v * s0) * gscale;
        float o3 = (n3v * c1 - n1v * s1) * gscale;
        unsigned short* d = dstb + (size_t)s * 64;
        d[lr]      = f2bf(o0);
        d[16 + lr] = f2bf(o1);
        d[32 + lr] = f2bf(o2);
        d[48 + lr] = f2bf(o3);
      }
    }
  } else {
    // V (bn 10,11): bf16 + transpose via LDS [2 heads][64 s][72 pad] -> vtb [d][s]
    unsigned short* sT = sAll;
#pragma unroll
    for (int m = 0; m < 2; m++)
#pragma unroll
      for (int j = 0; j < 4; j++) {
        const int srow = wm + m * 16 + lg * 4 + j;
#pragma unroll
        for (int n = 0; n < 4; n++)
          sT[(hsel * 64 + srow) * 72 + n * 16 + lr] = f2bf(acc[m][n][j]);
      }
    __syncthreads();
    const int hd = t >> 7;                 // head within block: 0/1
    const int d  = (t >> 1) & 63;
    const int sh = t & 1;                  // s-half: 0/1
    const int hk = 2 * (bn - 10) + hd;
    unsigned short* dst = vtb + ((size_t)((bb * 4 + hk) * 64 + d)) * 2048 +
                          (int)(m0 & 2047) + sh * 32;
    ushort8 o;
#pragma unroll
    for (int c = 0; c < 4; ++c) {
#pragma unroll
      for (int k = 0; k < 8; ++k) o[k] = sT[(hd * 64 + sh * 32 + c * 8 + k) * 72 + d];
      *(ushort8*)(dst + c * 8) = o;
    }
  }
}

// ---------------- bf16 GEMM: C[M,N] f32 = A[M,K] * B[N,K]^T (out proj) ----------------
// Single-barrier double-buffered staging.
__global__ __launch_bounds__(256) void gemm_bt_kernel(
    const unsigned short* __restrict__ A, const unsigned short* __restrict__ B,
    float* __restrict__ C, int M, int N, int K, int nbn) {
  __shared__ unsigned short sA[2][64 * 64];
  __shared__ unsigned short sB[2][128 * 64];
  const int t = threadIdx.x;
  const int lane = t & 63;
  const int w = t >> 6;
  const int bm = blockIdx.x / nbn, bn = blockIdx.x % nbn;
  const long m0 = (long)bm * 64, n0 = (long)bn * 128;
  const int wm = (w >> 1) * 32, wn = (w & 1) * 64;
  const int lr = lane & 15, lg = lane >> 4;
  f32x4 acc[2][4];
#pragma unroll
  for (int i = 0; i < 2; i++)
#pragma unroll
    for (int j = 0; j < 4; j++) acc[i][j] = (f32x4){0.f, 0.f, 0.f, 0.f};

#define STAGE_BT(bufi, kk0)                                                             \
  do {                                                                                  \
    _Pragma("unroll")                                                                   \
    for (int i = 0; i < 2; i++) {                                                       \
      int chunk = i * 256 + t;                                                          \
      int r = chunk >> 3;                                                               \
      int c = (chunk & 7) << 3;                                                         \
      gload16(A + (m0 + r) * (long)K + (kk0) + c, (char*)&sA[bufi][0] + chunk * 16);    \
    }                                                                                   \
    _Pragma("unroll")                                                                   \
    for (int i = 0; i < 4; i++) {                                                       \
      int chunk = i * 256 + t;                                                          \
      int r = chunk >> 3;                                                               \
      int c = (chunk & 7) << 3;                                                         \
      gload16(B + (n0 + r) * (long)K + (kk0) + c, (char*)&sB[bufi][0] + chunk * 16);    \
    }                                                                                   \
  } while (0)

  STAGE_BT(0, 0);
  int cur = 0;
  for (int k0 = 0; k0 < K; k0 += 64) {
    __syncthreads();   // prefetched buf[cur] staged; prior compute done
    if (k0 + 64 < K) STAGE_BT(cur ^ 1, k0 + 64);
    const unsigned short* cA = &sA[cur][0];
    const unsigned short* cB = &sB[cur][0];
#pragma unroll
    for (int kk = 0; kk < 2; ++kk) {
      bf16x8 af[2], bfr[4];
#pragma unroll
      for (int m = 0; m < 2; m++)
        af[m] = *(const bf16x8*)&cA[(wm + m * 16 + lr) * 64 + kk * 32 + lg * 8];
#pragma unroll
      for (int n = 0; n < 4; n++)
        bfr[n] = *(const bf16x8*)&cB[(wn + n * 16 + lr) * 64 + kk * 32 + lg * 8];
#pragma unroll
      for (int m = 0; m < 2; m++)
#pragma unroll
        for (int n = 0; n < 4; n++)
          acc[m][n] = __builtin_amdgcn_mfma_f32_16x16x32_bf16(af[m], bfr[n], acc[m][n], 0, 0, 0);
    }
    cur ^= 1;
  }
#undef STAGE_BT
#pragma unroll
  for (int m = 0; m < 2; m++) {
#pragma unroll
    for (int n = 0; n < 4; n++) {
      long col = n0 + wn + n * 16 + lr;
#pragma unroll
      for (int j = 0; j < 4; j++) {
        long row = m0 + wm + m * 16 + lg * 4 + j;
        C[row * N + col] = acc[m][n][j];
      }
    }
  }
}

// ---------------- causal flash attention (measured-best: R15/R18) ----------------
// 4 waves / 256 threads; block = 64 q rows of one (b,h); KVBLK=64, K+V double-buffered
// LDS (32KB, multicast to all 4 waves). Fixed-max softmax (-M in MFMA C), raw v_exp_f32,
// balanced heavy-early qt pairing, hoisted staging pointers.
__global__ __launch_bounds__(256) void attn_kernel(
    const unsigned short* __restrict__ qb, const unsigned short* __restrict__ kb,
    const unsigned short* __restrict__ vtb, unsigned short* __restrict__ yb,
    const float* __restrict__ qg) {
  __shared__ unsigned short sK[2][64 * 64];
  __shared__ unsigned short sV[2][64 * 64];
  const int tid = threadIdx.x;
  const int lane = tid & 63;
  const int w = tid >> 6;
  const int u = blockIdx.x >> 5;
  const int qt = (u < 16) ? (31 - u) : (u - 16);   // balanced pairing, heavy early
  const int bh = blockIdx.x & 31;
  const int h = bh & 15;
  const int b = bh >> 4;
  const float M = 11.7f * fabsf(qg[h]);
  const int q0 = qt * 64 + w * 16;
  const unsigned short* Q  = qb  + (size_t)(b * 16 + h) * 2048 * 64;
  const unsigned short* Kp = kb  + (size_t)(b * 4 + (h >> 2)) * 2048 * 64;
  const unsigned short* Vp = vtb + (size_t)(b * 4 + (h >> 2)) * 64 * 2048;
  const int qc = lane & 15;
  const int g = lane >> 4;
  const int qrow = q0 + qc;
  const bf16x8 qf0 = *(const bf16x8*)(Q + (size_t)qrow * 64 + g * 8);
  const bf16x8 qf1 = *(const bf16x8*)(Q + (size_t)qrow * 64 + 32 + g * 8);
  const f32x4 negM = (f32x4){-M, -M, -M, -M};
  f32x4 acc[4];
  acc[0] = acc[1] = acc[2] = acc[3] = (f32x4){0.f, 0.f, 0.f, 0.f};
  float lsum = 0.f;
  const int nt = qt + 1;

  // hoisted staging pointers: 2 K-chunks + 2 V-chunks per thread
  const int r0 = tid >> 3, c0 = tid & 7;
  const int swz = ((c0 ^ (r0 & 7)) << 3);
  const unsigned short* gK = Kp + (size_t)r0 * 64 + swz;
  const unsigned short* gV = Vp + (size_t)r0 * 2048 + swz;

  gload16(gK,             (char*)&sK[0][0] + tid * 16);
  gload16(gK + 32 * 64,   (char*)&sK[0][0] + (tid + 256) * 16);
  gload16(gV,             (char*)&sV[0][0] + tid * 16);
  gload16(gV + 32 * 2048, (char*)&sV[0][0] + (tid + 256) * 16);
  gK += 64 * 64; gV += 64;

  int cur = 0;
  for (int t = 0; t < nt; ++t) {
    __syncthreads();   // drains vmcnt: buf[cur] staged; buf[cur^1] free
    if (t + 1 < nt) {  // prefetch next tile
      const int nb = cur ^ 1;
      gload16(gK,             (char*)&sK[nb][0] + tid * 16);
      gload16(gK + 32 * 64,   (char*)&sK[nb][0] + (tid + 256) * 16);
      gload16(gV,             (char*)&sV[nb][0] + tid * 16);
      gload16(gV + 32 * 2048, (char*)&sV[nb][0] + (tid + 256) * 16);
      gK += 64 * 64; gV += 64;
    }
    const unsigned short* sKc = &sK[cur][0];
    const unsigned short* sVc = &sV[cur][0];
    // ---- QK^T (C-in = -M: scores come out pre-shifted) ----
    f32x4 st[4];
    __builtin_amdgcn_s_setprio(1);
#pragma unroll
    for (int ks = 0; ks < 4; ++ks) {
      const int rr = ks * 16 + qc;
      bf16x8 kf0 = *(const bf16x8*)&sKc[rr * 64 + ((g ^ (rr & 7)) << 3)];
      bf16x8 kf1 = *(const bf16x8*)&sKc[rr * 64 + (((4 + g) ^ (rr & 7)) << 3)];
      f32x4 a = negM;
      a = __builtin_amdgcn_mfma_f32_16x16x32_bf16(kf0, qf0, a, 0, 0, 0);
      a = __builtin_amdgcn_mfma_f32_16x16x32_bf16(kf1, qf1, a, 0, 0, 0);
      st[ks] = a;
    }
    __builtin_amdgcn_s_setprio(0);
    if (t == nt - 1) {  // diagonal tile: within-tile causal mask
#pragma unroll
      for (int ks = 0; ks < 4; ++ks)
#pragma unroll
        for (int j = 0; j < 4; ++j)
          if (ks * 16 + g * 4 + j > w * 16 + qc) st[ks][j] = -1e30f;
    }
    // ---- fixed-max softmax: p = v_exp_f32(st), one instr/score ----
    short4v pb[4];
#pragma unroll
    for (int ks = 0; ks < 4; ++ks)
#pragma unroll
      for (int j = 0; j < 4; ++j) {
        float p = EXP2(st[ks][j]);
        lsum += p;
        pb[ks][j] = bfbits(p);
      }
    // ---- PV: Y^T += V^T * P^T ----
    __builtin_amdgcn_s_setprio(1);
#pragma unroll
    for (int ks = 0; ks < 4; ++ks) {
#pragma unroll
      for (int d = 0; d < 4; ++d) {
        const int rd = d * 16 + qc;
        const int el = rd * 64 + ((((ks * 2 + (g >> 1)) ^ (rd & 7)) << 3) + ((g & 1) << 2));
        short4v vf = *(const short4v*)&sVc[el];
        acc[d] = __builtin_amdgcn_mfma_f32_16x16x16bf16_1k(vf, pb[ks], acc[d], 0, 0, 0);
      }
    }
    __builtin_amdgcn_s_setprio(0);
    cur ^= 1;
  }
  float l = lsum;
  l += __shfl_xor(l, 16);
  l += __shfl_xor(l, 32);
  const float inv = 1.0f / l;
  unsigned short* Y = yb + (size_t)(b * 2048 + qrow) * 1024 + h * 64;
#pragma unroll
  for (int d = 0; d < 4; ++d) {
    ushort4v o;
#pragma unroll
    for (int j = 0; j < 4; ++j) o[j] = (unsigned short)bfbits(acc[d][j] * inv);
    *(ushort4v*)(Y + d * 16 + g * 4) = o;
  }
}

extern "C" void kernel_launch(void* const* d_in, const int* in_sizes, int n_in,
                              void* d_out, int out_size, void* d_ws, size_t ws_size,
                              hipStream_t stream) {
  const float* x  = (const float*)d_in[0];
  const float* Wq = (const float*)d_in[1];
  const float* Wk = (const float*)d_in[2];
  const float* Wv = (const float*)d_in[3];
  const float* Wo = (const float*)d_in[4];
  const float* qg = (const float*)d_in[5];
  float* out = (float*)d_out;

  char* ws = (char*)d_ws;
  const size_t NEED = 35127296;
  if (ws_size < NEED) return;
  unsigned short* xb   = (unsigned short*)(ws);                 // 8,388,608
  unsigned short* wqkv = (unsigned short*)(ws + 8388608);       // 3,145,728
  unsigned short* wo_b = (unsigned short*)(ws + 11534336);      // 2,097,152
  unsigned short* qbuf = (unsigned short*)(ws + 13631488);      // 8,388,608
  unsigned short* kbuf = (unsigned short*)(ws + 22020096);      // 2,097,152
  unsigned short* vtb  = (unsigned short*)(ws + 24117248);      // 2,097,152
  unsigned short* ybuf = (unsigned short*)(ws + 26214400);      // 8,388,608
  float*          tab  = (float*)        (ws + 34603008);       // 524,288

  prep_kernel<<<6912, 256, 0, stream>>>(x, Wq, Wk, Wv, Wo, xb, wqkv, wo_b, tab);
  gemm_qkv_kernel<<<64 * 12, 256, 0, stream>>>(xb, wqkv, tab, qg, qbuf, kbuf, vtb);
  attn_kernel<<<1024, 256, 0, stream>>>(qbuf, kbuf, vtb, ybuf, qg);
  gemm_bt_kernel<<<64 * 8, 256, 0, stream>>>(ybuf, wo_b, out, 4096, 1024, 1024, 8);
}